// Round 7
// baseline (127.668 us; speedup 1.0000x reference)
//
#include <hip/hip_runtime.h>
#include <stdint.h>

typedef __attribute__((ext_vector_type(4)))  int i32x4;
typedef __attribute__((ext_vector_type(16))) int i32x16;

// ws layout:
//   xm: uint4 [b=512][z=8][s=16]  (4 x u32 k-bitplanes)   1 MB
//   Bp: i8    [z=8][p=2][sl=8][j=128][k=128]              2 MB
//   pt: f32   [z=8][b=512][j=128]                         2 MB
#define XM_OFF 0u
#define BP_OFF 1048576u
#define PT_OFF 3145728u

__device__ __forceinline__ uint32_t q16(float v){
  float f = fminf(fmaxf(rintf(v*4096.f), -32768.f), 32767.f);
  return (uint32_t)(int)f & 0xffffu;
}

// ---------- fused pack: x -> bit-planes (ballot transpose), w -> 2-bit slice planes ----------
__global__ __launch_bounds__(256) void pack_k(const float* __restrict__ x, const float* __restrict__ w,
                                              uint4* __restrict__ xm, uint32_t* __restrict__ Bw){
  const int lane = threadIdx.x & 63;
  if (blockIdx.x < 1024){
    // one wave per (b, z): transpose 128 xint16 values into 16 s-bitplanes of 4 u32
    int wv = blockIdx.x*4 + (threadIdx.x >> 6);       // 0..4095
    int b = wv >> 3, z = wv & 7;
    const float* xp = x + b*1024 + z*128;
    uint32_t u0 = q16(xp[lane]);
    uint32_t u1 = q16(xp[lane + 64]);
    uint4 out4 = {0,0,0,0};
    #pragma unroll
    for (int s = 0; s < 16; ++s){
      unsigned long long m0 = __ballot((u0 >> s) & 1u);
      unsigned long long m1 = __ballot((u1 >> s) & 1u);
      if (lane == s){
        out4.x = (uint32_t)m0; out4.y = (uint32_t)(m0 >> 32);
        out4.z = (uint32_t)m1; out4.w = (uint32_t)(m1 >> 32);
      }
    }
    if (lane < 16) xm[(b*8 + z)*16 + lane] = out4;
  } else {
    int t = (blockIdx.x - 1024)*256 + threadIdx.x;    // 32768
    int j = t >> 8, kq = t & 255;
    int r = kq >> 5, kd = kq & 31;
    float4 v = *reinterpret_cast<const float4*>(w + j*1024 + kq*4);
    #pragma unroll
    for (int p = 0; p < 2; ++p){
      uint32_t q0 = (uint32_t)fminf(rintf(fmaxf(p ? -v.x : v.x, 0.f)*4096.f), 65535.f);
      uint32_t q1 = (uint32_t)fminf(rintf(fmaxf(p ? -v.y : v.y, 0.f)*4096.f), 65535.f);
      uint32_t q2 = (uint32_t)fminf(rintf(fmaxf(p ? -v.z : v.z, 0.f)*4096.f), 65535.f);
      uint32_t q3 = (uint32_t)fminf(rintf(fmaxf(p ? -v.w : v.w, 0.f)*4096.f), 65535.f);
      #pragma unroll
      for (int sl = 0; sl < 8; ++sl){
        int sh = 2*(7 - sl);
        uint32_t word = ((q0 >> sh) & 3u) | (((q1 >> sh) & 3u) << 8)
                      | (((q2 >> sh) & 3u) << 16) | (((q3 >> sh) & 3u) << 24);
        Bw[(((r*2 + p)*8 + sl)*128 + j)*32 + kd] = word;
      }
    }
  }
}

// ---------- main MFMA kernel: branch-free static loop over the 10 live tiles ----------
__global__ __launch_bounds__(512, 4) void mvm_main_k(const uint4* __restrict__ xm,
                                                     const uint8_t* __restrict__ Bp,
                                                     float* __restrict__ partial){
  __shared__ uint8_t lds[65536];                      // 16 slots x 4KB
  __shared__ uint32_t flg[8];
  const int tid = threadIdx.x, lane = tid & 63, wid = tid >> 6;
  const int z = blockIdx.z, jblk = blockIdx.y;
  const int col = lane & 31, hi = lane >> 5;

  // ---- stage all 16 (p,sl) tiles, swizzled; record per-slot nonzero flags ----
  {
    const int q = lane >> 3, cS = (lane & 7) ^ q;
    uint32_t f2 = 0;
    #pragma unroll
    for (int u = 0; u < 2; ++u){
      const int si = wid + u*8;
      const uint8_t* src = Bp + ((size_t)((z*16 + si)*128 + jblk*32) << 7);
      uint4 r0 = *(const uint4*)(src + (q     )*128 + cS*16);
      uint4 r1 = *(const uint4*)(src + (q +  8)*128 + cS*16);
      uint4 r2 = *(const uint4*)(src + (q + 16)*128 + cS*16);
      uint4 r3 = *(const uint4*)(src + (q + 24)*128 + cS*16);
      uint8_t* dst = lds + si*4096 + lane*16;
      *(uint4*)(dst       ) = r0;
      *(uint4*)(dst + 1024) = r1;
      *(uint4*)(dst + 2048) = r2;
      *(uint4*)(dst + 3072) = r3;
      uint32_t o = r0.x|r0.y|r0.z|r0.w | r1.x|r1.y|r1.z|r1.w
                 | r2.x|r2.y|r2.z|r2.w | r3.x|r3.y|r3.z|r3.w;
      f2 |= (__any(o != 0u) ? 1u : 0u) << u;
    }
    if (lane == 0) flg[wid] = f2;
  }

  // ---- A fragments for TWO b-pairs (4 b per wave) ----
  const int bb  = blockIdx.x*32 + wid*4;
  const int s_a = lane & 15;
  const uint4 pwA = xm[((bb     + (col >> 4))*8 + z)*16 + s_a];
  const uint4 pwB = xm[((bb + 2 + (col >> 4))*8 + z)*16 + s_a];
  i32x4 afrA[4], afrB[4];
  {
    const uint32_t wA[4] = {pwA.x, pwA.y, pwA.z, pwA.w};
    const uint32_t wB[4] = {pwB.x, pwB.y, pwB.z, pwB.w};
    #pragma unroll
    for (int f = 0; f < 4; ++f){
      uint32_t plA = wA[f] >> (hi*16);
      uint32_t plB = wB[f] >> (hi*16);
      #pragma unroll
      for (int wI = 0; wI < 4; ++wI){
        afrA[f][wI] = (int)((((plA >> (wI*4)) & 0xFu) * 0x204081u) & 0x01010101u);
        afrB[f][wI] = (int)((((plB >> (wI*4)) & 0xFu) * 0x204081u) & 0x01010101u);
      }
    }
  }
  __syncthreads();

  uint32_t msk = 0;
  #pragma unroll
  for (int w2 = 0; w2 < 8; ++w2){
    uint32_t f2 = flg[w2];
    msk |= (f2 & 1u) << w2;
    msk |= ((f2 >> 1) & 1u) << (w2 + 8);
  }
  msk = (uint32_t)__builtin_amdgcn_readfirstlane((int)msk);

  const int c7 = col & 7;
  const int xo0 = ((0 + hi) ^ c7) << 4;
  const int xo1 = ((2 + hi) ^ c7) << 4;
  const int xo2 = ((4 + hi) ^ c7) << 4;
  const int xo3 = ((6 + hi) ^ c7) << 4;

  i32x16 zz;
  #pragma unroll
  for (int i = 0; i < 16; ++i) zz[i] = 0;

  const float C1 = (float)(511.0/384.0);
  const float QC = (float)(384.0/511.0/4096.0);
  const float sc = hi ? 16.0f : 1.0f;                 // 2^(4*hi)
  const float w7 = hi ? -8.0f : 8.0f;                 // stream 15 (s_lo=11, hi=1) is negative
  float accA0[2] = {0.f, 0.f}, accA1[2] = {0.f, 0.f};
  float accB0[2] = {0.f, 0.f}, accB1[2] = {0.f, 0.f};

// per-tile ADC + slice/stream shift-add into 2 scalars per C-tile.
#define EPI(cc, A0, A1, slwv, slw256) do { \
    float nf[16]; \
    _Pragma("unroll") \
    for (int g_ = 0; g_ < 16; ++g_) nf[g_] = rintf((float)cc[g_] * C1); \
    float t0 = fmaf(nf[1], 2.f, nf[0]);  t0 = fmaf(nf[2], 4.f, t0);  t0 = fmaf(nf[3], 8.f, t0); \
    float t1 = fmaf(nf[5], 2.f, nf[4]);  t1 = fmaf(nf[6], 4.f, t1);  t1 = fmaf(nf[7], w7, t1); \
    float t2 = fmaf(nf[9], 2.f, nf[8]);  t2 = fmaf(nf[10],4.f, t2);  t2 = fmaf(nf[11],8.f, t2); \
    float t3 = fmaf(nf[13],2.f, nf[12]); t3 = fmaf(nf[14],4.f, t3);  t3 = fmaf(nf[15],w7, t3); \
    A0 = fmaf(t0, slwv, A0);  A0 = fmaf(t1, slw256, A0); \
    A1 = fmaf(t2, slwv, A1);  A1 = fmaf(t3, slw256, A1); \
  } while (0)

#define TILE_BODY(ti_, p_) do { \
    const float slwv_   = (float)(1 << (14 - 2*((ti_) & 7)));  /* 4^(7-sl) */ \
    const float slw256_ = slwv_ * 256.0f; \
    const uint8_t* lb_ = lds + (ti_)*4096 + col*128; \
    i32x4 b0_ = *(const i32x4*)(lb_ + xo0); \
    i32x4 b1_ = *(const i32x4*)(lb_ + xo1); \
    i32x4 b2_ = *(const i32x4*)(lb_ + xo2); \
    i32x4 b3_ = *(const i32x4*)(lb_ + xo3); \
    __builtin_amdgcn_s_setprio(1); \
    i32x16 cc_ = __builtin_amdgcn_mfma_i32_32x32x32_i8(afrA[0], b0_, zz, 0, 0, 0); \
    cc_ = __builtin_amdgcn_mfma_i32_32x32x32_i8(afrA[1], b1_, cc_, 0, 0, 0); \
    cc_ = __builtin_amdgcn_mfma_i32_32x32x32_i8(afrA[2], b2_, cc_, 0, 0, 0); \
    cc_ = __builtin_amdgcn_mfma_i32_32x32x32_i8(afrA[3], b3_, cc_, 0, 0, 0); \
    i32x16 cd_ = __builtin_amdgcn_mfma_i32_32x32x32_i8(afrB[0], b0_, zz, 0, 0, 0); \
    cd_ = __builtin_amdgcn_mfma_i32_32x32x32_i8(afrB[1], b1_, cd_, 0, 0, 0); \
    cd_ = __builtin_amdgcn_mfma_i32_32x32x32_i8(afrB[2], b2_, cd_, 0, 0, 0); \
    cd_ = __builtin_amdgcn_mfma_i32_32x32x32_i8(afrB[3], b3_, cd_, 0, 0, 0); \
    __builtin_amdgcn_s_setprio(0); \
    EPI(cc_, accA0[p_], accA1[p_], slwv_, slw256_); \
    EPI(cd_, accB0[p_], accB1[p_], slwv_, slw256_); \
  } while (0)

  // ---- main: the 10 tiles that are nonzero for any plausible weight scale ----
  // (slices 3..7 of each path; p0/p1 interleaved for independent chains)
  TILE_BODY(3, 0);  TILE_BODY(11, 1);
  TILE_BODY(4, 0);  TILE_BODY(12, 1);
  TILE_BODY(5, 0);  TILE_BODY(13, 1);
  TILE_BODY(6, 0);  TILE_BODY(14, 1);
  TILE_BODY(7, 0);  TILE_BODY(15, 1);

  // ---- correction: slices 0..2 (bits 15:10) — empty unless |w| >= 0.25; flag-guarded ----
  if (msk & (1u <<  0)) TILE_BODY(0, 0);
  if (msk & (1u <<  1)) TILE_BODY(1, 0);
  if (msk & (1u <<  2)) TILE_BODY(2, 0);
  if (msk & (1u <<  8)) TILE_BODY(8, 1);
  if (msk & (1u <<  9)) TILE_BODY(9, 1);
  if (msk & (1u << 10)) TILE_BODY(10, 1);

#undef TILE_BODY
#undef EPI

  // ---- per-path accumulator quantization, pos - neg, store ----
  float oA0, oA1, oB0, oB1;
  {
    float a, q0, q1;
    a = accA0[0]*sc; a += __shfl_xor(a, 32);
    q0 = fminf(fmaxf(rintf(a*QC)*(1.0f/4096.0f), -8.0f), 8.0f - 1.0f/4096.0f);
    a = accA0[1]*sc; a += __shfl_xor(a, 32);
    q1 = fminf(fmaxf(rintf(a*QC)*(1.0f/4096.0f), -8.0f), 8.0f - 1.0f/4096.0f);
    oA0 = q0 - q1;
    a = accA1[0]*sc; a += __shfl_xor(a, 32);
    q0 = fminf(fmaxf(rintf(a*QC)*(1.0f/4096.0f), -8.0f), 8.0f - 1.0f/4096.0f);
    a = accA1[1]*sc; a += __shfl_xor(a, 32);
    q1 = fminf(fmaxf(rintf(a*QC)*(1.0f/4096.0f), -8.0f), 8.0f - 1.0f/4096.0f);
    oA1 = q0 - q1;
    a = accB0[0]*sc; a += __shfl_xor(a, 32);
    q0 = fminf(fmaxf(rintf(a*QC)*(1.0f/4096.0f), -8.0f), 8.0f - 1.0f/4096.0f);
    a = accB0[1]*sc; a += __shfl_xor(a, 32);
    q1 = fminf(fmaxf(rintf(a*QC)*(1.0f/4096.0f), -8.0f), 8.0f - 1.0f/4096.0f);
    oB0 = q0 - q1;
    a = accB1[0]*sc; a += __shfl_xor(a, 32);
    q0 = fminf(fmaxf(rintf(a*QC)*(1.0f/4096.0f), -8.0f), 8.0f - 1.0f/4096.0f);
    a = accB1[1]*sc; a += __shfl_xor(a, 32);
    q1 = fminf(fmaxf(rintf(a*QC)*(1.0f/4096.0f), -8.0f), 8.0f - 1.0f/4096.0f);
    oB1 = q0 - q1;
  }

  const int jout = jblk*32 + col;
  partial[(z*512 + bb + hi    )*128 + jout] = hi ? oA1 : oA0;
  partial[(z*512 + bb + 2 + hi)*128 + jout] = hi ? oB1 : oB0;
}

__global__ __launch_bounds__(256) void reduce_k(const float* __restrict__ partial,
                                                const float* __restrict__ bias,
                                                float* __restrict__ out){
  int t = blockIdx.x*256 + threadIdx.x;               // 65536
  int b = t >> 7, j = t & 127;
  float s = 0.f;
  #pragma unroll
  for (int z = 0; z < 8; ++z) s += partial[(z*512 + b)*128 + j];  // exact multiples of 2^-12
  out[t] = s + bias[j];
}

extern "C" void kernel_launch(void* const* d_in, const int* in_sizes, int n_in,
                              void* d_out, int out_size, void* d_ws, size_t ws_size,
                              hipStream_t stream){
  const float* x    = (const float*)d_in[0];
  const float* w    = (const float*)d_in[1];
  const float* bias = (const float*)d_in[2];
  uint8_t* ws = (uint8_t*)d_ws;

  hipLaunchKernelGGL(pack_k, dim3(1152), dim3(256), 0, stream,
                     x, w, (uint4*)(ws + XM_OFF), (uint32_t*)(ws + BP_OFF));
  hipLaunchKernelGGL(mvm_main_k, dim3(16, 4, 8), dim3(512), 0, stream,
                     (const uint4*)(ws + XM_OFF), ws + BP_OFF, (float*)(ws + PT_OFF));
  hipLaunchKernelGGL(reduce_k, dim3(256), dim3(256), 0, stream,
                     (const float*)(ws + PT_OFF), bias, (float*)d_out);
}

// Round 8
// 33.280 us; speedup vs baseline: 3.8361x; 3.8361x over previous
//
#include <hip/hip_runtime.h>
#include <stdint.h>

typedef __attribute__((ext_vector_type(4)))  int i32x4;
typedef __attribute__((ext_vector_type(16))) int i32x16;

// ws layout:
//   xm:   uint4 [b=512][z=8][s=16]  (4 x u32 k-bitplanes)   1 MB
//   Bp:   i8    [z=8][p=2][sl=8][j=128][k=128]              2 MB
//   mask: u32   [z=8][jblk=4], bit (p*8+sl)                 128 B (4KB slot)
//   pt:   f32   [z=8][b=512][j=128]                         2 MB
#define XM_OFF 0u
#define BP_OFF 1048576u
#define MK_OFF 3145728u
#define PT_OFF 3149824u

__device__ __forceinline__ uint32_t q16(float v){
  float f = fminf(fmaxf(rintf(v*4096.f), -32768.f), 32767.f);
  return (uint32_t)(int)f & 0xffffu;
}

// ---------- fused pack: x -> bit-planes (ballot transpose), w -> 2-bit slice planes + mask ----------
__global__ __launch_bounds__(256) void pack_k(const float* __restrict__ x, const float* __restrict__ w,
                                              uint4* __restrict__ xm, uint32_t* __restrict__ Bw,
                                              uint32_t* __restrict__ mask){
  const int lane = threadIdx.x & 63;
  if (blockIdx.x < 1024){
    // one wave per (b, z): transpose 128 xint16 values into 16 s-bitplanes of 4 u32
    int wv = blockIdx.x*4 + (threadIdx.x >> 6);       // 0..4095
    int b = wv >> 3, z = wv & 7;
    const float* xp = x + b*1024 + z*128;
    uint32_t u0 = q16(xp[lane]);
    uint32_t u1 = q16(xp[lane + 64]);
    uint4 out4 = {0,0,0,0};
    #pragma unroll
    for (int s = 0; s < 16; ++s){
      unsigned long long m0 = __ballot((u0 >> s) & 1u);
      unsigned long long m1 = __ballot((u1 >> s) & 1u);
      if (lane == s){
        out4.x = (uint32_t)m0; out4.y = (uint32_t)(m0 >> 32);
        out4.z = (uint32_t)m1; out4.w = (uint32_t)(m1 >> 32);
      }
    }
    if (lane < 16) xm[(b*8 + z)*16 + lane] = out4;
  } else {
    int t = (blockIdx.x - 1024)*256 + threadIdx.x;    // 32768
    int j = t >> 8, kq = t & 255;
    int r = kq >> 5, kd = kq & 31;
    float4 v = *reinterpret_cast<const float4*>(w + j*1024 + kq*4);
    uint32_t lm = 0;
    #pragma unroll
    for (int p = 0; p < 2; ++p){
      uint32_t q0 = (uint32_t)fminf(rintf(fmaxf(p ? -v.x : v.x, 0.f)*4096.f), 65535.f);
      uint32_t q1 = (uint32_t)fminf(rintf(fmaxf(p ? -v.y : v.y, 0.f)*4096.f), 65535.f);
      uint32_t q2 = (uint32_t)fminf(rintf(fmaxf(p ? -v.z : v.z, 0.f)*4096.f), 65535.f);
      uint32_t q3 = (uint32_t)fminf(rintf(fmaxf(p ? -v.w : v.w, 0.f)*4096.f), 65535.f);
      #pragma unroll
      for (int sl = 0; sl < 8; ++sl){
        int sh = 2*(7 - sl);
        uint32_t word = ((q0 >> sh) & 3u) | (((q1 >> sh) & 3u) << 8)
                      | (((q2 >> sh) & 3u) << 16) | (((q3 >> sh) & 3u) << 24);
        Bw[(((r*2 + p)*8 + sl)*128 + j)*32 + kd] = word;
        lm |= (word != 0u ? 1u : 0u) << (p*8 + sl);
      }
    }
    // OR-reduce within each 32-lane half (half shares same (r, jblk))
    lm |= (uint32_t)__shfl_xor((int)lm, 16);
    lm |= (uint32_t)__shfl_xor((int)lm, 8);
    lm |= (uint32_t)__shfl_xor((int)lm, 4);
    lm |= (uint32_t)__shfl_xor((int)lm, 2);
    lm |= (uint32_t)__shfl_xor((int)lm, 1);
    if ((threadIdx.x & 31) == 0) atomicOr(&mask[r*4 + (j >> 5)], lm);
  }
}

// ---------- main MFMA kernel: r6 skeleton, mask-gated staging, sequential EPIs ----------
__global__ __launch_bounds__(512, 4) void mvm_main_k(const uint4* __restrict__ xm,
                                                     const uint8_t* __restrict__ Bp,
                                                     const uint32_t* __restrict__ mask,
                                                     float* __restrict__ partial){
  __shared__ uint8_t lds[65536];                      // 16 slots x 4KB
  const int tid = threadIdx.x, lane = tid & 63, wid = tid >> 6;
  const int z = blockIdx.z, jblk = blockIdx.y;
  const int col = lane & 31, hi = lane >> 5;

  const uint32_t msk = (uint32_t)__builtin_amdgcn_readfirstlane((int)(mask[z*4 + jblk] & 0xFFFFu));

  // ---- stage the nonzero (p,sl) tiles only, swizzled (chunk ^= row&7) ----
  {
    const int q = lane >> 3, cS = (lane & 7) ^ q;
    #pragma unroll
    for (int u = 0; u < 2; ++u){
      const int si = wid + u*8;
      if (msk & (1u << si)){
        const uint8_t* src = Bp + ((size_t)((z*16 + si)*128 + jblk*32) << 7);
        uint4 r0 = *(const uint4*)(src + (q     )*128 + cS*16);
        uint4 r1 = *(const uint4*)(src + (q +  8)*128 + cS*16);
        uint4 r2 = *(const uint4*)(src + (q + 16)*128 + cS*16);
        uint4 r3 = *(const uint4*)(src + (q + 24)*128 + cS*16);
        uint8_t* dst = lds + si*4096 + lane*16;
        *(uint4*)(dst       ) = r0;
        *(uint4*)(dst + 1024) = r1;
        *(uint4*)(dst + 2048) = r2;
        *(uint4*)(dst + 3072) = r3;
      }
    }
  }

  // ---- A fragments for TWO b-pairs (4 b per wave), verified mapping ----
  const int bb  = blockIdx.x*32 + wid*4;
  const int s_a = lane & 15;
  const uint4 pwA = xm[((bb     + (col >> 4))*8 + z)*16 + s_a];
  const uint4 pwB = xm[((bb + 2 + (col >> 4))*8 + z)*16 + s_a];
  i32x4 afrA[4], afrB[4];
  {
    const uint32_t wA[4] = {pwA.x, pwA.y, pwA.z, pwA.w};
    const uint32_t wB[4] = {pwB.x, pwB.y, pwB.z, pwB.w};
    #pragma unroll
    for (int f = 0; f < 4; ++f){
      uint32_t plA = wA[f] >> (hi*16);
      uint32_t plB = wB[f] >> (hi*16);
      #pragma unroll
      for (int wI = 0; wI < 4; ++wI){
        afrA[f][wI] = (int)((((plA >> (wI*4)) & 0xFu) * 0x204081u) & 0x01010101u);
        afrB[f][wI] = (int)((((plB >> (wI*4)) & 0xFu) * 0x204081u) & 0x01010101u);
      }
    }
  }
  __syncthreads();

  const int c7 = col & 7;
  const int xo0 = ((0 + hi) ^ c7) << 4;
  const int xo1 = ((2 + hi) ^ c7) << 4;
  const int xo2 = ((4 + hi) ^ c7) << 4;
  const int xo3 = ((6 + hi) ^ c7) << 4;

  i32x16 zz;
  #pragma unroll
  for (int i = 0; i < 16; ++i) zz[i] = 0;

  const float C1 = (float)(511.0/384.0);
  const float QC = (float)(384.0/511.0/4096.0);
  const float sc = hi ? 16.0f : 1.0f;                 // 2^(4*hi)
  const float w7 = hi ? -8.0f : 8.0f;                 // stream 15 (s_lo=11, hi=1) is negative
  float oA0 = 0.f, oA1 = 0.f, oB0 = 0.f, oB1 = 0.f;

// per-tile ADC + slice/stream shift-add into 2 scalars per C-tile.
#define EPI(cc, A0, A1) do { \
    float nf[16]; \
    _Pragma("unroll") \
    for (int g_ = 0; g_ < 16; ++g_) nf[g_] = rintf((float)cc[g_] * C1); \
    float t0 = fmaf(nf[1], 2.f, nf[0]);  t0 = fmaf(nf[2], 4.f, t0);  t0 = fmaf(nf[3], 8.f, t0); \
    float t1 = fmaf(nf[5], 2.f, nf[4]);  t1 = fmaf(nf[6], 4.f, t1);  t1 = fmaf(nf[7], w7, t1); \
    float t2 = fmaf(nf[9], 2.f, nf[8]);  t2 = fmaf(nf[10],4.f, t2);  t2 = fmaf(nf[11],8.f, t2); \
    float t3 = fmaf(nf[13],2.f, nf[12]); t3 = fmaf(nf[14],4.f, t3);  t3 = fmaf(nf[15],w7, t3); \
    A0 = fmaf(t0, slwv, A0);  A0 = fmaf(t1, slw256, A0); \
    A1 = fmaf(t2, slwv, A1);  A1 = fmaf(t3, slw256, A1); \
  } while (0)

  #pragma unroll
  for (int p = 0; p < 2; ++p){
    float aA0 = 0.f, aA1 = 0.f, aB0 = 0.f, aB1 = 0.f;
    #pragma unroll
    for (int sl = 0; sl < 8; ++sl){
      const int ti = p*8 + sl;
      if (msk & (1u << ti)){
        const float slwv   = (float)(1 << (14 - 2*sl));  // 4^(7-sl)
        const float slw256 = slwv * 256.0f;
        const uint8_t* lb = lds + ti*4096 + col*128;
        i32x4 b0 = *(const i32x4*)(lb + xo0);
        i32x4 b1 = *(const i32x4*)(lb + xo1);
        i32x4 b2 = *(const i32x4*)(lb + xo2);
        i32x4 b3 = *(const i32x4*)(lb + xo3);
        // chain A, consume immediately; then chain B (bounds i32x16 liveness to one at a time)
        {
          __builtin_amdgcn_s_setprio(1);
          i32x16 cc = __builtin_amdgcn_mfma_i32_32x32x32_i8(afrA[0], b0, zz, 0, 0, 0);
          cc = __builtin_amdgcn_mfma_i32_32x32x32_i8(afrA[1], b1, cc, 0, 0, 0);
          cc = __builtin_amdgcn_mfma_i32_32x32x32_i8(afrA[2], b2, cc, 0, 0, 0);
          cc = __builtin_amdgcn_mfma_i32_32x32x32_i8(afrA[3], b3, cc, 0, 0, 0);
          __builtin_amdgcn_s_setprio(0);
          EPI(cc, aA0, aA1);
        }
        {
          __builtin_amdgcn_s_setprio(1);
          i32x16 cd = __builtin_amdgcn_mfma_i32_32x32x32_i8(afrB[0], b0, zz, 0, 0, 0);
          cd = __builtin_amdgcn_mfma_i32_32x32x32_i8(afrB[1], b1, cd, 0, 0, 0);
          cd = __builtin_amdgcn_mfma_i32_32x32x32_i8(afrB[2], b2, cd, 0, 0, 0);
          cd = __builtin_amdgcn_mfma_i32_32x32x32_i8(afrB[3], b3, cd, 0, 0, 0);
          __builtin_amdgcn_s_setprio(0);
          EPI(cd, aB0, aB1);
        }
      }
    }

    aA0 *= sc; aA1 *= sc; aB0 *= sc; aB1 *= sc;
    aA0 += __shfl_xor(aA0, 32); aA1 += __shfl_xor(aA1, 32);
    aB0 += __shfl_xor(aB0, 32); aB1 += __shfl_xor(aB1, 32);

    float qA0 = fminf(fmaxf(rintf(aA0*QC)*(1.0f/4096.0f), -8.0f), 8.0f - 1.0f/4096.0f);
    float qA1 = fminf(fmaxf(rintf(aA1*QC)*(1.0f/4096.0f), -8.0f), 8.0f - 1.0f/4096.0f);
    float qB0 = fminf(fmaxf(rintf(aB0*QC)*(1.0f/4096.0f), -8.0f), 8.0f - 1.0f/4096.0f);
    float qB1 = fminf(fmaxf(rintf(aB1*QC)*(1.0f/4096.0f), -8.0f), 8.0f - 1.0f/4096.0f);
    if (p == 0){ oA0 += qA0; oA1 += qA1; oB0 += qB0; oB1 += qB1; }
    else       { oA0 -= qA0; oA1 -= qA1; oB0 -= qB0; oB1 -= qB1; }
  }
#undef EPI

  const int jout = jblk*32 + col;
  partial[(z*512 + bb + hi    )*128 + jout] = hi ? oA1 : oA0;
  partial[(z*512 + bb + 2 + hi)*128 + jout] = hi ? oB1 : oB0;
}

__global__ __launch_bounds__(256) void reduce_k(const float* __restrict__ partial,
                                                const float* __restrict__ bias,
                                                float* __restrict__ out){
  int t = blockIdx.x*256 + threadIdx.x;               // 65536
  int b = t >> 7, j = t & 127;
  float s = 0.f;
  #pragma unroll
  for (int z = 0; z < 8; ++z) s += partial[(z*512 + b)*128 + j];  // exact multiples of 2^-12
  out[t] = s + bias[j];
}

extern "C" void kernel_launch(void* const* d_in, const int* in_sizes, int n_in,
                              void* d_out, int out_size, void* d_ws, size_t ws_size,
                              hipStream_t stream){
  const float* x    = (const float*)d_in[0];
  const float* w    = (const float*)d_in[1];
  const float* bias = (const float*)d_in[2];
  uint8_t* ws = (uint8_t*)d_ws;

  hipMemsetAsync(ws + MK_OFF, 0, 128, stream);
  hipLaunchKernelGGL(pack_k, dim3(1152), dim3(256), 0, stream,
                     x, w, (uint4*)(ws + XM_OFF), (uint32_t*)(ws + BP_OFF), (uint32_t*)(ws + MK_OFF));
  hipLaunchKernelGGL(mvm_main_k, dim3(16, 4, 8), dim3(512), 0, stream,
                     (const uint4*)(ws + XM_OFF), ws + BP_OFF,
                     (const uint32_t*)(ws + MK_OFF), (float*)(ws + PT_OFF));
  hipLaunchKernelGGL(reduce_k, dim3(256), dim3(256), 0, stream,
                     (const float*)(ws + PT_OFF), bias, (float*)d_out);
}

// Round 9
// 27.041 us; speedup vs baseline: 4.7212x; 1.2307x over previous
//
#include <hip/hip_runtime.h>
#include <stdint.h>

typedef __attribute__((ext_vector_type(4)))  int i32x4;
typedef __attribute__((ext_vector_type(16))) int i32x16;

// ws layout:
//   xm: uint4 [b=512][z=8][s=16]  (4 x u32 k-bitplanes)   1 MB
//   Bp: i8    [z=8][p=2][sl=8][j=128][k=128]              2 MB
//   pt: f32   [z=8][b=512][j=128]                         2 MB
#define XM_OFF 0u
#define BP_OFF 1048576u
#define PT_OFF 3145728u

__device__ __forceinline__ uint32_t q16(float v){
  float f = fminf(fmaxf(rintf(v*4096.f), -32768.f), 32767.f);
  return (uint32_t)(int)f & 0xffffu;
}

// ---------- fused pack: x -> bit-planes (ballot transpose), w -> 2-bit slice planes ----------
__global__ __launch_bounds__(256) void pack_k(const float* __restrict__ x, const float* __restrict__ w,
                                              uint4* __restrict__ xm, uint32_t* __restrict__ Bw){
  const int lane = threadIdx.x & 63;
  if (blockIdx.x < 1024){
    // one wave per (b, z): transpose 128 xint16 values into 16 s-bitplanes of 4 u32
    int wv = blockIdx.x*4 + (threadIdx.x >> 6);       // 0..4095
    int b = wv >> 3, z = wv & 7;
    const float* xp = x + b*1024 + z*128;
    uint32_t u0 = q16(xp[lane]);
    uint32_t u1 = q16(xp[lane + 64]);
    uint4 out4 = {0,0,0,0};
    #pragma unroll
    for (int s = 0; s < 16; ++s){
      unsigned long long m0 = __ballot((u0 >> s) & 1u);
      unsigned long long m1 = __ballot((u1 >> s) & 1u);
      if (lane == s){
        out4.x = (uint32_t)m0; out4.y = (uint32_t)(m0 >> 32);
        out4.z = (uint32_t)m1; out4.w = (uint32_t)(m1 >> 32);
      }
    }
    if (lane < 16) xm[(b*8 + z)*16 + lane] = out4;
  } else {
    int t = (blockIdx.x - 1024)*256 + threadIdx.x;    // 32768
    int j = t >> 8, kq = t & 255;
    int r = kq >> 5, kd = kq & 31;
    float4 v = *reinterpret_cast<const float4*>(w + j*1024 + kq*4);
    #pragma unroll
    for (int p = 0; p < 2; ++p){
      uint32_t q0 = (uint32_t)fminf(rintf(fmaxf(p ? -v.x : v.x, 0.f)*4096.f), 65535.f);
      uint32_t q1 = (uint32_t)fminf(rintf(fmaxf(p ? -v.y : v.y, 0.f)*4096.f), 65535.f);
      uint32_t q2 = (uint32_t)fminf(rintf(fmaxf(p ? -v.z : v.z, 0.f)*4096.f), 65535.f);
      uint32_t q3 = (uint32_t)fminf(rintf(fmaxf(p ? -v.w : v.w, 0.f)*4096.f), 65535.f);
      #pragma unroll
      for (int sl = 0; sl < 8; ++sl){
        int sh = 2*(7 - sl);
        uint32_t word = ((q0 >> sh) & 3u) | (((q1 >> sh) & 3u) << 8)
                      | (((q2 >> sh) & 3u) << 16) | (((q3 >> sh) & 3u) << 24);
        Bw[(((r*2 + p)*8 + sl)*128 + j)*32 + kd] = word;
      }
    }
  }
}

// ---------- main MFMA kernel: r6 skeleton + interleaved chains + wave-parity p-stagger ----------
__global__ __launch_bounds__(512, 4) void mvm_main_k(const uint4* __restrict__ xm,
                                                     const uint8_t* __restrict__ Bp,
                                                     float* __restrict__ partial){
  __shared__ uint8_t lds[65536];                      // 16 slots x 4KB
  __shared__ uint32_t flg[8];
  const int tid = threadIdx.x, lane = tid & 63, wid = tid >> 6;
  const int z = blockIdx.z, jblk = blockIdx.y;
  const int col = lane & 31, hi = lane >> 5;

  // ---- stage all 16 (p,sl) tiles, swizzled; record per-slot nonzero flags ----
  {
    const int q = lane >> 3, cS = (lane & 7) ^ q;
    uint32_t f2 = 0;
    #pragma unroll
    for (int u = 0; u < 2; ++u){
      const int si = wid + u*8;
      const uint8_t* src = Bp + ((size_t)((z*16 + si)*128 + jblk*32) << 7);
      uint4 r0 = *(const uint4*)(src + (q     )*128 + cS*16);
      uint4 r1 = *(const uint4*)(src + (q +  8)*128 + cS*16);
      uint4 r2 = *(const uint4*)(src + (q + 16)*128 + cS*16);
      uint4 r3 = *(const uint4*)(src + (q + 24)*128 + cS*16);
      uint8_t* dst = lds + si*4096 + lane*16;
      *(uint4*)(dst       ) = r0;
      *(uint4*)(dst + 1024) = r1;
      *(uint4*)(dst + 2048) = r2;
      *(uint4*)(dst + 3072) = r3;
      uint32_t o = r0.x|r0.y|r0.z|r0.w | r1.x|r1.y|r1.z|r1.w
                 | r2.x|r2.y|r2.z|r2.w | r3.x|r3.y|r3.z|r3.w;
      f2 |= (__any(o != 0u) ? 1u : 0u) << u;
    }
    if (lane == 0) flg[wid] = f2;
  }

  // ---- A fragments for TWO b-pairs (4 b per wave) ----
  const int bb  = blockIdx.x*32 + wid*4;
  const int s_a = lane & 15;
  const uint4 pwA = xm[((bb     + (col >> 4))*8 + z)*16 + s_a];
  const uint4 pwB = xm[((bb + 2 + (col >> 4))*8 + z)*16 + s_a];
  i32x4 afrA[4], afrB[4];
  {
    const uint32_t wA[4] = {pwA.x, pwA.y, pwA.z, pwA.w};
    const uint32_t wB[4] = {pwB.x, pwB.y, pwB.z, pwB.w};
    #pragma unroll
    for (int f = 0; f < 4; ++f){
      uint32_t plA = wA[f] >> (hi*16);
      uint32_t plB = wB[f] >> (hi*16);
      #pragma unroll
      for (int wI = 0; wI < 4; ++wI){
        afrA[f][wI] = (int)((((plA >> (wI*4)) & 0xFu) * 0x204081u) & 0x01010101u);
        afrB[f][wI] = (int)((((plB >> (wI*4)) & 0xFu) * 0x204081u) & 0x01010101u);
      }
    }
  }
  __syncthreads();

  uint32_t msk = 0;
  #pragma unroll
  for (int w2 = 0; w2 < 8; ++w2){
    uint32_t f2 = flg[w2];
    msk |= (f2 & 1u) << w2;
    msk |= ((f2 >> 1) & 1u) << (w2 + 8);
  }
  msk = (uint32_t)__builtin_amdgcn_readfirstlane((int)msk);

  const int c7 = col & 7;
  const int xo0 = ((0 + hi) ^ c7) << 4;
  const int xo1 = ((2 + hi) ^ c7) << 4;
  const int xo2 = ((4 + hi) ^ c7) << 4;
  const int xo3 = ((6 + hi) ^ c7) << 4;

  i32x16 zz;
  #pragma unroll
  for (int i = 0; i < 16; ++i) zz[i] = 0;

  const float C1 = (float)(511.0/384.0);
  const float QC = (float)(384.0/511.0/4096.0);
  const float sc = hi ? 16.0f : 1.0f;                 // 2^(4*hi)
  const float w7 = hi ? -8.0f : 8.0f;                 // stream 15 (s_lo=11, hi=1) is negative
  float oA0 = 0.f, oA1 = 0.f, oB0 = 0.f, oB1 = 0.f;

  // wave-parity phase stagger: odd waves run p=1 first (scalar-uniform)
  const int pfirst = __builtin_amdgcn_readfirstlane(wid & 1);

#define EPI(cc, A0, A1) do { \
    float nf[16]; \
    _Pragma("unroll") \
    for (int g_ = 0; g_ < 16; ++g_) nf[g_] = rintf((float)cc[g_] * C1); \
    float t0 = fmaf(nf[1], 2.f, nf[0]);  t0 = fmaf(nf[2], 4.f, t0);  t0 = fmaf(nf[3], 8.f, t0); \
    float t1 = fmaf(nf[5], 2.f, nf[4]);  t1 = fmaf(nf[6], 4.f, t1);  t1 = fmaf(nf[7], w7, t1); \
    float t2 = fmaf(nf[9], 2.f, nf[8]);  t2 = fmaf(nf[10],4.f, t2);  t2 = fmaf(nf[11],8.f, t2); \
    float t3 = fmaf(nf[13],2.f, nf[12]); t3 = fmaf(nf[14],4.f, t3);  t3 = fmaf(nf[15],w7, t3); \
    A0 = fmaf(t0, slwv, A0);  A0 = fmaf(t1, slw256, A0); \
    A1 = fmaf(t2, slwv, A1);  A1 = fmaf(t3, slw256, A1); \
  } while (0)

  #pragma unroll
  for (int pi = 0; pi < 2; ++pi){
    const int p = pi ^ pfirst;                        // scalar-uniform
    const int tbase = p*8;
    float aA0 = 0.f, aA1 = 0.f, aB0 = 0.f, aB1 = 0.f;
    #pragma unroll
    for (int sl = 0; sl < 8; ++sl){
      if (msk & (1u << (tbase + sl))){
        const float slwv   = (float)(1 << (14 - 2*sl));  // 4^(7-sl)
        const float slw256 = slwv * 256.0f;
        const uint8_t* lb = lds + (size_t)(tbase + sl)*4096 + col*128;
        i32x4 b0 = *(const i32x4*)(lb + xo0);
        i32x4 b1 = *(const i32x4*)(lb + xo1);
        i32x4 b2 = *(const i32x4*)(lb + xo2);
        i32x4 b3 = *(const i32x4*)(lb + xo3);
        // interleaved independent chains: matrix pipe gets an issue-ready MFMA every slot
        i32x16 cc = __builtin_amdgcn_mfma_i32_32x32x32_i8(afrA[0], b0, zz, 0, 0, 0);
        i32x16 cd = __builtin_amdgcn_mfma_i32_32x32x32_i8(afrB[0], b0, zz, 0, 0, 0);
        cc = __builtin_amdgcn_mfma_i32_32x32x32_i8(afrA[1], b1, cc, 0, 0, 0);
        cd = __builtin_amdgcn_mfma_i32_32x32x32_i8(afrB[1], b1, cd, 0, 0, 0);
        cc = __builtin_amdgcn_mfma_i32_32x32x32_i8(afrA[2], b2, cc, 0, 0, 0);
        cd = __builtin_amdgcn_mfma_i32_32x32x32_i8(afrB[2], b2, cd, 0, 0, 0);
        cc = __builtin_amdgcn_mfma_i32_32x32x32_i8(afrA[3], b3, cc, 0, 0, 0);
        cd = __builtin_amdgcn_mfma_i32_32x32x32_i8(afrB[3], b3, cd, 0, 0, 0);
        EPI(cc, aA0, aA1);
        EPI(cd, aB0, aB1);
      }
    }

    aA0 *= sc; aA1 *= sc; aB0 *= sc; aB1 *= sc;
    aA0 += __shfl_xor(aA0, 32); aA1 += __shfl_xor(aA1, 32);
    aB0 += __shfl_xor(aB0, 32); aB1 += __shfl_xor(aB1, 32);

    float qA0 = fminf(fmaxf(rintf(aA0*QC)*(1.0f/4096.0f), -8.0f), 8.0f - 1.0f/4096.0f);
    float qA1 = fminf(fmaxf(rintf(aA1*QC)*(1.0f/4096.0f), -8.0f), 8.0f - 1.0f/4096.0f);
    float qB0 = fminf(fmaxf(rintf(aB0*QC)*(1.0f/4096.0f), -8.0f), 8.0f - 1.0f/4096.0f);
    float qB1 = fminf(fmaxf(rintf(aB1*QC)*(1.0f/4096.0f), -8.0f), 8.0f - 1.0f/4096.0f);
    const float sgn = p ? -1.0f : 1.0f;               // exact: pos path adds, neg path subtracts
    oA0 = fmaf(qA0, sgn, oA0); oA1 = fmaf(qA1, sgn, oA1);
    oB0 = fmaf(qB0, sgn, oB0); oB1 = fmaf(qB1, sgn, oB1);
  }
#undef EPI

  const int jout = jblk*32 + col;
  partial[(z*512 + bb + hi    )*128 + jout] = hi ? oA1 : oA0;
  partial[(z*512 + bb + 2 + hi)*128 + jout] = hi ? oB1 : oB0;
}

__global__ __launch_bounds__(256) void reduce_k(const float* __restrict__ partial,
                                                const float* __restrict__ bias,
                                                float* __restrict__ out){
  int t = blockIdx.x*256 + threadIdx.x;               // 65536
  int b = t >> 7, j = t & 127;
  float s = 0.f;
  #pragma unroll
  for (int z = 0; z < 8; ++z) s += partial[(z*512 + b)*128 + j];  // exact multiples of 2^-12
  out[t] = s + bias[j];
}

extern "C" void kernel_launch(void* const* d_in, const int* in_sizes, int n_in,
                              void* d_out, int out_size, void* d_ws, size_t ws_size,
                              hipStream_t stream){
  const float* x    = (const float*)d_in[0];
  const float* w    = (const float*)d_in[1];
  const float* bias = (const float*)d_in[2];
  uint8_t* ws = (uint8_t*)d_ws;

  hipLaunchKernelGGL(pack_k, dim3(1152), dim3(256), 0, stream,
                     x, w, (uint4*)(ws + XM_OFF), (uint32_t*)(ws + BP_OFF));
  hipLaunchKernelGGL(mvm_main_k, dim3(16, 4, 8), dim3(512), 0, stream,
                     (const uint4*)(ws + XM_OFF), ws + BP_OFF, (float*)(ws + PT_OFF));
  hipLaunchKernelGGL(reduce_k, dim3(256), dim3(256), 0, stream,
                     (const float*)(ws + PT_OFF), bias, (float*)d_out);
}

// Round 10
// 24.903 us; speedup vs baseline: 5.1266x; 1.0859x over previous
//
#include <hip/hip_runtime.h>
#include <stdint.h>

typedef __attribute__((ext_vector_type(4)))  int i32x4;
typedef __attribute__((ext_vector_type(16))) int i32x16;

// ws layout:
//   xm: uint4 [b=512][z=8][s=16]  (4 x u32 k-bitplanes)   1 MB
//   Bp: i8    [z=8][p=2][sl=8][j=128][k=128]              2 MB
#define XM_OFF 0u
#define BP_OFF 1048576u

__device__ __forceinline__ uint32_t q16(float v){
  float f = fminf(fmaxf(rintf(v*4096.f), -32768.f), 32767.f);
  return (uint32_t)(int)f & 0xffffu;
}

// ---------- fused pack: x -> bit-planes, w -> 2-bit slice planes, out <- quantized bias ----------
__global__ __launch_bounds__(256) void pack_k(const float* __restrict__ x, const float* __restrict__ w,
                                              const float* __restrict__ bias,
                                              uint4* __restrict__ xm, uint32_t* __restrict__ Bw,
                                              float* __restrict__ out){
  const int lane = threadIdx.x & 63;
  if (blockIdx.x < 1024){
    // one wave per (b, z): transpose 128 xint16 values into 16 s-bitplanes of 4 u32
    int wv = blockIdx.x*4 + (threadIdx.x >> 6);       // 0..4095
    int b = wv >> 3, z = wv & 7;
    const float* xp = x + b*1024 + z*128;
    uint32_t u0 = q16(xp[lane]);
    uint32_t u1 = q16(xp[lane + 64]);
    uint4 out4 = {0,0,0,0};
    #pragma unroll
    for (int s = 0; s < 16; ++s){
      unsigned long long m0 = __ballot((u0 >> s) & 1u);
      unsigned long long m1 = __ballot((u1 >> s) & 1u);
      if (lane == s){
        out4.x = (uint32_t)m0; out4.y = (uint32_t)(m0 >> 32);
        out4.z = (uint32_t)m1; out4.w = (uint32_t)(m1 >> 32);
      }
    }
    if (lane < 16) xm[(b*8 + z)*16 + lane] = out4;
  } else if (blockIdx.x < 1152){
    int t = (blockIdx.x - 1024)*256 + threadIdx.x;    // 32768
    int j = t >> 8, kq = t & 255;
    int r = kq >> 5, kd = kq & 31;
    float4 v = *reinterpret_cast<const float4*>(w + j*1024 + kq*4);
    #pragma unroll
    for (int p = 0; p < 2; ++p){
      uint32_t q0 = (uint32_t)fminf(rintf(fmaxf(p ? -v.x : v.x, 0.f)*4096.f), 65535.f);
      uint32_t q1 = (uint32_t)fminf(rintf(fmaxf(p ? -v.y : v.y, 0.f)*4096.f), 65535.f);
      uint32_t q2 = (uint32_t)fminf(rintf(fmaxf(p ? -v.z : v.z, 0.f)*4096.f), 65535.f);
      uint32_t q3 = (uint32_t)fminf(rintf(fmaxf(p ? -v.w : v.w, 0.f)*4096.f), 65535.f);
      #pragma unroll
      for (int sl = 0; sl < 8; ++sl){
        int sh = 2*(7 - sl);
        uint32_t word = ((q0 >> sh) & 3u) | (((q1 >> sh) & 3u) << 8)
                      | (((q2 >> sh) & 3u) << 16) | (((q3 >> sh) & 3u) << 24);
        Bw[(((r*2 + p)*8 + sl)*128 + j)*32 + kd] = word;
      }
    }
  } else {
    // out <- bias rounded to 2^-12 grid: all later atomic adds are exact & order-free
    int t = (blockIdx.x - 1152)*256 + threadIdx.x;    // 65536
    out[t] = rintf(bias[t & 127]*4096.f)*(1.0f/4096.0f);
  }
}

// ---------- main MFMA kernel: r9 skeleton, atomic output (reduce kernel eliminated) ----------
__global__ __launch_bounds__(512, 4) void mvm_main_k(const uint4* __restrict__ xm,
                                                     const uint8_t* __restrict__ Bp,
                                                     float* __restrict__ out){
  __shared__ uint8_t lds[65536];                      // 16 slots x 4KB
  __shared__ uint32_t flg[8];
  const int tid = threadIdx.x, lane = tid & 63, wid = tid >> 6;
  const int z = blockIdx.z, jblk = blockIdx.y;
  const int col = lane & 31, hi = lane >> 5;

  // ---- stage all 16 (p,sl) tiles, swizzled; record per-slot nonzero flags ----
  {
    const int q = lane >> 3, cS = (lane & 7) ^ q;
    uint32_t f2 = 0;
    #pragma unroll
    for (int u = 0; u < 2; ++u){
      const int si = wid + u*8;
      const uint8_t* src = Bp + ((size_t)((z*16 + si)*128 + jblk*32) << 7);
      uint4 r0 = *(const uint4*)(src + (q     )*128 + cS*16);
      uint4 r1 = *(const uint4*)(src + (q +  8)*128 + cS*16);
      uint4 r2 = *(const uint4*)(src + (q + 16)*128 + cS*16);
      uint4 r3 = *(const uint4*)(src + (q + 24)*128 + cS*16);
      uint8_t* dst = lds + si*4096 + lane*16;
      *(uint4*)(dst       ) = r0;
      *(uint4*)(dst + 1024) = r1;
      *(uint4*)(dst + 2048) = r2;
      *(uint4*)(dst + 3072) = r3;
      uint32_t o = r0.x|r0.y|r0.z|r0.w | r1.x|r1.y|r1.z|r1.w
                 | r2.x|r2.y|r2.z|r2.w | r3.x|r3.y|r3.z|r3.w;
      f2 |= (__any(o != 0u) ? 1u : 0u) << u;
    }
    if (lane == 0) flg[wid] = f2;
  }

  // ---- A fragments for TWO b-pairs (4 b per wave) ----
  const int bb  = blockIdx.x*32 + wid*4;
  const int s_a = lane & 15;
  const uint4 pwA = xm[((bb     + (col >> 4))*8 + z)*16 + s_a];
  const uint4 pwB = xm[((bb + 2 + (col >> 4))*8 + z)*16 + s_a];
  i32x4 afrA[4], afrB[4];
  {
    const uint32_t wA[4] = {pwA.x, pwA.y, pwA.z, pwA.w};
    const uint32_t wB[4] = {pwB.x, pwB.y, pwB.z, pwB.w};
    #pragma unroll
    for (int f = 0; f < 4; ++f){
      uint32_t plA = wA[f] >> (hi*16);
      uint32_t plB = wB[f] >> (hi*16);
      #pragma unroll
      for (int wI = 0; wI < 4; ++wI){
        afrA[f][wI] = (int)((((plA >> (wI*4)) & 0xFu) * 0x204081u) & 0x01010101u);
        afrB[f][wI] = (int)((((plB >> (wI*4)) & 0xFu) * 0x204081u) & 0x01010101u);
      }
    }
  }
  __syncthreads();

  uint32_t msk = 0;
  #pragma unroll
  for (int w2 = 0; w2 < 8; ++w2){
    uint32_t f2 = flg[w2];
    msk |= (f2 & 1u) << w2;
    msk |= ((f2 >> 1) & 1u) << (w2 + 8);
  }
  msk = (uint32_t)__builtin_amdgcn_readfirstlane((int)msk);

  const int c7 = col & 7;
  const int xo0 = ((0 + hi) ^ c7) << 4;
  const int xo1 = ((2 + hi) ^ c7) << 4;
  const int xo2 = ((4 + hi) ^ c7) << 4;
  const int xo3 = ((6 + hi) ^ c7) << 4;

  i32x16 zz;
  #pragma unroll
  for (int i = 0; i < 16; ++i) zz[i] = 0;

  const float C1 = (float)(511.0/384.0);
  const float QC = (float)(384.0/511.0/4096.0);
  const float sc = hi ? 16.0f : 1.0f;                 // 2^(4*hi)
  const float w7 = hi ? -8.0f : 8.0f;                 // stream 15 (s_lo=11, hi=1) is negative
  float oA0 = 0.f, oA1 = 0.f, oB0 = 0.f, oB1 = 0.f;

  // wave-parity phase stagger: odd waves run p=1 first (scalar-uniform)
  const int pfirst = __builtin_amdgcn_readfirstlane(wid & 1);

#define EPI(cc, A0, A1) do { \
    float nf[16]; \
    _Pragma("unroll") \
    for (int g_ = 0; g_ < 16; ++g_) nf[g_] = rintf((float)cc[g_] * C1); \
    float t0 = fmaf(nf[1], 2.f, nf[0]);  t0 = fmaf(nf[2], 4.f, t0);  t0 = fmaf(nf[3], 8.f, t0); \
    float t1 = fmaf(nf[5], 2.f, nf[4]);  t1 = fmaf(nf[6], 4.f, t1);  t1 = fmaf(nf[7], w7, t1); \
    float t2 = fmaf(nf[9], 2.f, nf[8]);  t2 = fmaf(nf[10],4.f, t2);  t2 = fmaf(nf[11],8.f, t2); \
    float t3 = fmaf(nf[13],2.f, nf[12]); t3 = fmaf(nf[14],4.f, t3);  t3 = fmaf(nf[15],w7, t3); \
    A0 = fmaf(t0, slwv, A0);  A0 = fmaf(t1, slw256, A0); \
    A1 = fmaf(t2, slwv, A1);  A1 = fmaf(t3, slw256, A1); \
  } while (0)

  #pragma unroll
  for (int pi = 0; pi < 2; ++pi){
    const int p = pi ^ pfirst;                        // scalar-uniform
    const int tbase = p*8;
    float aA0 = 0.f, aA1 = 0.f, aB0 = 0.f, aB1 = 0.f;
    #pragma unroll
    for (int sl = 0; sl < 8; ++sl){
      if (msk & (1u << (tbase + sl))){
        const float slwv   = (float)(1 << (14 - 2*sl));  // 4^(7-sl)
        const float slw256 = slwv * 256.0f;
        const uint8_t* lb = lds + (size_t)(tbase + sl)*4096 + col*128;
        i32x4 b0 = *(const i32x4*)(lb + xo0);
        i32x4 b1 = *(const i32x4*)(lb + xo1);
        i32x4 b2 = *(const i32x4*)(lb + xo2);
        i32x4 b3 = *(const i32x4*)(lb + xo3);
        // interleaved independent chains: matrix pipe gets an issue-ready MFMA every slot
        i32x16 cc = __builtin_amdgcn_mfma_i32_32x32x32_i8(afrA[0], b0, zz, 0, 0, 0);
        i32x16 cd = __builtin_amdgcn_mfma_i32_32x32x32_i8(afrB[0], b0, zz, 0, 0, 0);
        cc = __builtin_amdgcn_mfma_i32_32x32x32_i8(afrA[1], b1, cc, 0, 0, 0);
        cd = __builtin_amdgcn_mfma_i32_32x32x32_i8(afrB[1], b1, cd, 0, 0, 0);
        cc = __builtin_amdgcn_mfma_i32_32x32x32_i8(afrA[2], b2, cc, 0, 0, 0);
        cd = __builtin_amdgcn_mfma_i32_32x32x32_i8(afrB[2], b2, cd, 0, 0, 0);
        cc = __builtin_amdgcn_mfma_i32_32x32x32_i8(afrA[3], b3, cc, 0, 0, 0);
        cd = __builtin_amdgcn_mfma_i32_32x32x32_i8(afrB[3], b3, cd, 0, 0, 0);
        EPI(cc, aA0, aA1);
        EPI(cd, aB0, aB1);
      }
    }

    aA0 *= sc; aA1 *= sc; aB0 *= sc; aB1 *= sc;
    aA0 += __shfl_xor(aA0, 32); aA1 += __shfl_xor(aA1, 32);
    aB0 += __shfl_xor(aB0, 32); aB1 += __shfl_xor(aB1, 32);

    float qA0 = fminf(fmaxf(rintf(aA0*QC)*(1.0f/4096.0f), -8.0f), 8.0f - 1.0f/4096.0f);
    float qA1 = fminf(fmaxf(rintf(aA1*QC)*(1.0f/4096.0f), -8.0f), 8.0f - 1.0f/4096.0f);
    float qB0 = fminf(fmaxf(rintf(aB0*QC)*(1.0f/4096.0f), -8.0f), 8.0f - 1.0f/4096.0f);
    float qB1 = fminf(fmaxf(rintf(aB1*QC)*(1.0f/4096.0f), -8.0f), 8.0f - 1.0f/4096.0f);
    const float sgn = p ? -1.0f : 1.0f;
    oA0 = fmaf(qA0, sgn, oA0); oA1 = fmaf(qA1, sgn, oA1);
    oB0 = fmaf(qB0, sgn, oB0); oB1 = fmaf(qB1, sgn, oB1);
  }
#undef EPI

  // exact float atomics: all addends are multiples of 2^-12, partial sums < 2^7+1
  // -> every intermediate exactly representable -> order-independent & deterministic
  const int jout = jblk*32 + col;
  atomicAdd(&out[(bb + hi    )*128 + jout], hi ? oA1 : oA0);
  atomicAdd(&out[(bb + 2 + hi)*128 + jout], hi ? oB1 : oB0);
}

extern "C" void kernel_launch(void* const* d_in, const int* in_sizes, int n_in,
                              void* d_out, int out_size, void* d_ws, size_t ws_size,
                              hipStream_t stream){
  const float* x    = (const float*)d_in[0];
  const float* w    = (const float*)d_in[1];
  const float* bias = (const float*)d_in[2];
  uint8_t* ws = (uint8_t*)d_ws;
  float* out = (float*)d_out;

  hipLaunchKernelGGL(pack_k, dim3(1408), dim3(256), 0, stream,
                     x, w, bias, (uint4*)(ws + XM_OFF), (uint32_t*)(ws + BP_OFF), out);
  hipLaunchKernelGGL(mvm_main_k, dim3(16, 4, 8), dim3(512), 0, stream,
                     (const uint4*)(ws + XM_OFF), ws + BP_OFF, out);
}